// Round 15
// baseline (380.674 us; speedup 1.0000x reference)
//
#include <hip/hip_runtime.h>
#include <hip/hip_bf16.h>

#define NN 50000
#define NE 800000
#define DD 64
#define NL 3
#define NE_PAD (NE + NN * 16)   // worst-case padded edge count (1.6M, 12.8 MB)

__device__ __forceinline__ float rlane(float v, int l) {
    return __int_as_float(__builtin_amdgcn_readlane(__float_as_int(v), l));
}

// ---------------------------------------------------------------------------
// CSR build, step 1: in-degree histogram; atomicAdd return = edge's rank
// within its dst segment (stored contiguously) -> atomic-free reorder.
// ---------------------------------------------------------------------------
__global__ void hist_kernel(const int* __restrict__ dst,
                            int* __restrict__ deg,
                            int* __restrict__ rank) {
    int t = blockIdx.x * blockDim.x + threadIdx.x;
    int e = t * 4;
    if (e + 4 <= NE) {
        int4 d4 = *reinterpret_cast<const int4*>(dst + e);
        int r0 = atomicAdd(&deg[d4.x], 1);
        int r1 = atomicAdd(&deg[d4.y], 1);
        int r2 = atomicAdd(&deg[d4.z], 1);
        int r3 = atomicAdd(&deg[d4.w], 1);
        *reinterpret_cast<int4*>(rank + e) = make_int4(r0, r1, r2, r3);
    } else {
        for (int i = e; i < NE; ++i) rank[i] = atomicAdd(&deg[dst[i]], 1);
    }
}

// ---------------------------------------------------------------------------
// CSR build, step 2: unordered segment allocation, degrees rounded up to x16
// (pad slots stay zero from the e_sw memset -> (src=0, w=0.0) no-op edges).
// ---------------------------------------------------------------------------
__global__ void alloc_kernel(const int* __restrict__ deg,
                             int* __restrict__ row_start,
                             int* __restrict__ counter) {
    int n = blockIdx.x * blockDim.x + threadIdx.x;
    int lane = threadIdx.x & 63;
    int d = (n < NN) ? ((deg[n] + 15) & ~15) : 0;
    int s = d;
    #pragma unroll
    for (int off = 1; off < 64; off <<= 1) {
        int t = __shfl_up(s, off);
        if (lane >= off) s += t;
    }
    int total = __shfl(s, 63);
    int base = 0;
    if (lane == 63) base = atomicAdd(counter, total);
    base = __shfl(base, 63);
    int my = base + s - d;
    if (n < NN) row_start[n] = my;
}

// ---------------------------------------------------------------------------
// CSR build, step 3: reorder edges to row_start[dst] + rank -- no atomics.
// ---------------------------------------------------------------------------
__global__ void reorder_kernel(const int* __restrict__ src,
                               const int* __restrict__ dst,
                               const float* __restrict__ w,
                               const int* __restrict__ rank,
                               const int* __restrict__ row_start,
                               int2* __restrict__ e_sw) {
    int t = blockIdx.x * blockDim.x + threadIdx.x;
    int e = t * 2;
    if (e + 2 <= NE) {
        int2   s2 = *reinterpret_cast<const int2*>(src + e);
        int2   d2 = *reinterpret_cast<const int2*>(dst + e);
        float2 w2 = *reinterpret_cast<const float2*>(w + e);
        int2   r2 = *reinterpret_cast<const int2*>(rank + e);
        e_sw[row_start[d2.x] + r2.x] = make_int2(s2.x, __float_as_int(w2.x));
        e_sw[row_start[d2.y] + r2.y] = make_int2(s2.y, __float_as_int(w2.y));
    } else {
        for (int i = e; i < NE; ++i) {
            e_sw[row_start[dst[i]] + rank[i]] = make_int2(src[i], __float_as_int(w[i]));
        }
    }
}

// ---------------------------------------------------------------------------
// Fused layer (round-14): gather + dense in one wave/node pass; agg NEVER
// touches memory. Gather = round-13's 4-rows-per-dwordx4 scheme (padded x16
// segments, s_load edge meta, cndmask distribution, shfl_xor butterfly).
// After the butterfly, lanes 0-15 hold agg[n] as float4 (tx..tw) -> the
// dense phase readlane-broadcasts agg[k] and h[n][k] straight from registers
// against W columns (W re-read from L1 per node; round-13 counter-reading
// showed the compiler never kept W in VGPRs anyway and it's ~free).
// (256,3): 76-100 VGPR spill-free (round-8 lesson: tighter caps spill).
// Writes hout != h (other waves still gather-read h) -> ping-pong buffers.
// ---------------------------------------------------------------------------
template<bool LAST>
__global__ void __launch_bounds__(256, 3)
fused_kernel(const float* __restrict__ h,
             const int* __restrict__ row_start,
             const int* __restrict__ deg,
             const int2* __restrict__ e_sw,
             const float* __restrict__ Wrel,
             const float* __restrict__ Wroot,
             const float* __restrict__ b,
             float* __restrict__ hout) {
    const int lane = threadIdx.x & 63;
    const int g    = lane >> 4;          // edge sub-group 0..3
    const int cq   = (lane & 15) << 2;   // 4-column base within the row
    const int wid0 = (int)((blockIdx.x * blockDim.x + threadIdx.x) >> 6);
    const int nw   = (gridDim.x * blockDim.x) >> 6;
    const float bias = b[lane];

    for (int nn = wid0; nn < NN; nn += nw) {
        const int n    = __builtin_amdgcn_readfirstlane(nn);
        const int beg  = __builtin_amdgcn_readfirstlane(row_start[n]);
        const int rdeg = __builtin_amdgcn_readfirstlane((deg[n] + 15) & ~15);

        // ---- gather: 4 edges per dwordx4 instruction ----
        float ax0=0.f, ay0=0.f, az0=0.f, aw0=0.f;
        float ax1=0.f, ay1=0.f, az1=0.f, aw1=0.f;
        float ax2=0.f, ay2=0.f, az2=0.f, aw2=0.f;
        float ax3=0.f, ay3=0.f, az3=0.f, aw3=0.f;
        for (int i = 0; i < rdeg; i += 16) {
            const int2* ep = e_sw + beg + i;   // uniform -> s_load path
            int2 m0 = ep[0],  m1 = ep[1],  m2 = ep[2],  m3 = ep[3];
            int2 m4 = ep[4],  m5 = ep[5],  m6 = ep[6],  m7 = ep[7];
            int2 m8 = ep[8],  m9 = ep[9],  m10= ep[10], m11= ep[11];
            int2 m12= ep[12], m13= ep[13], m14= ep[14], m15= ep[15];
#define SLOT(AX,AY,AZ,AW, EA,EB,EC,ED)                                          \
            {                                                                   \
                int  srcg = (g==0) ? EA.x : (g==1) ? EB.x : (g==2) ? EC.x : ED.x;\
                int  wig  = (g==0) ? EA.y : (g==1) ? EB.y : (g==2) ? EC.y : ED.y;\
                float wg  = __int_as_float(wig);                                \
                const float4 r = *reinterpret_cast<const float4*>(              \
                    h + (size_t)srcg * DD + cq);                                \
                AX += wg * r.x; AY += wg * r.y; AZ += wg * r.z; AW += wg * r.w; \
            }
            SLOT(ax0,ay0,az0,aw0, m0,m1,m2,m3)
            SLOT(ax1,ay1,az1,aw1, m4,m5,m6,m7)
            SLOT(ax2,ay2,az2,aw2, m8,m9,m10,m11)
            SLOT(ax3,ay3,az3,aw3, m12,m13,m14,m15)
#undef SLOT
        }
        float tx = (ax0+ax1)+(ax2+ax3);
        float ty = (ay0+ay1)+(ay2+ay3);
        float tz = (az0+az1)+(az2+az3);
        float tw = (aw0+aw1)+(aw2+aw3);
        tx += __shfl_xor(tx, 16); tx += __shfl_xor(tx, 32);
        ty += __shfl_xor(ty, 16); ty += __shfl_xor(ty, 32);
        tz += __shfl_xor(tz, 16); tz += __shfl_xor(tz, 32);
        tw += __shfl_xor(tw, 16); tw += __shfl_xor(tw, 32);
        // lanes 0-15 now hold agg[n][4q..4q+3] in (tx,ty,tz,tw)

        // own row for the root term (lanes with equal q load the same 16B)
        const float4 hv = *reinterpret_cast<const float4*>(h + (size_t)n * DD + cq);

        // ---- dense: out[n][lane] = bias + sum_k agg[k]*Wrel[k][lane]
        //                                  + h[n][k]*Wroot[k][lane] ----
        float a0 = bias, a1 = 0.f, a2 = 0.f, a3 = 0.f;
#define DK(K, ACC, TC, HC)                                                      \
        ACC += rlane(TC, (K) >> 2) * Wrel[(K) * DD + lane]                      \
             + rlane(HC, (K) >> 2) * Wroot[(K) * DD + lane];
        #pragma unroll
        for (int k = 0; k < DD; k += 4) {
            DK(k + 0, a0, tx, hv.x)
            DK(k + 1, a1, ty, hv.y)
            DK(k + 2, a2, tz, hv.z)
            DK(k + 3, a3, tw, hv.w)
        }
#undef DK
        float r = (a0 + a1) + (a2 + a3);
        if (LAST) r = tanhf(r);
        hout[(size_t)n * DD + lane] = r;
    }
}

extern "C" void kernel_launch(void* const* d_in, const int* in_sizes, int n_in,
                              void* d_out, int out_size, void* d_ws, size_t ws_size,
                              hipStream_t stream) {
    const float* x     = (const float*)d_in[0];
    const int*   ei    = (const int*)d_in[1];
    const float* ew    = (const float*)d_in[2];
    const float* Wrel  = (const float*)d_in[3];
    const float* brel  = (const float*)d_in[4];
    const float* Wroot = (const float*)d_in[5];
    float* out = (float*)d_out;

    // Workspace (~42 MB of 256 MiB). e_sw/deg/counter contiguous -> ONE memset.
    float* hA        = (float*)d_ws;                    // NN*DD f32 (12.8 MB)
    float* hB        = hA + (size_t)NN * DD;            // NN*DD f32 (12.8 MB)
    int2*  e_sw      = (int2*)(hB + (size_t)NN * DD);   // NE_PAD int2 (12.8 MB)
    int*   deg       = (int*)(e_sw + NE_PAD);           // NN
    int*   counter   = deg + NN;                        // 1
    int*   row_start = counter + 1;                     // NN
    int*   rank      = row_start + NN;                  // NE (3.2 MB)

    const int* src = ei;            // edge_index[0]
    const int* dst = ei + NE;       // edge_index[1]

    const int hblocks = (NE / 4 + 255) / 256;           // 782
    const int rblocks = (NE / 2 + 255) / 256;           // 1563
    const int ablocks = (NN + 255) / 256;               // 196
    const int fblocks = 1563;                           // 6252 waves, ~8 nodes/wave

    // ---- CSR build: one memset covers e_sw pads + deg + counter ----
    hipMemsetAsync(e_sw, 0, (size_t)NE_PAD * sizeof(int2) + (size_t)(NN + 1) * sizeof(int), stream);
    hist_kernel<<<hblocks, 256, 0, stream>>>(dst, deg, rank);
    alloc_kernel<<<ablocks, 256, 0, stream>>>(deg, row_start, counter);
    reorder_kernel<<<rblocks, 256, 0, stream>>>(src, dst, ew, rank, row_start, e_sw);

    // ---- 3 fused layers: x -> hA -> hB -> out ----
    fused_kernel<false><<<fblocks, 256, 0, stream>>>(x,  row_start, deg, e_sw, Wrel,           Wroot,           brel,        hA);
    fused_kernel<false><<<fblocks, 256, 0, stream>>>(hA, row_start, deg, e_sw, Wrel + DD*DD,   Wroot + DD*DD,   brel + DD,   hB);
    fused_kernel<true ><<<fblocks, 256, 0, stream>>>(hB, row_start, deg, e_sw, Wrel + 2*DD*DD, Wroot + 2*DD*DD, brel + 2*DD, out);
}

// Round 16
// 301.141 us; speedup vs baseline: 1.2641x; 1.2641x over previous
//
#include <hip/hip_runtime.h>
#include <hip/hip_bf16.h>

#define NN 50000
#define NE 800000
#define DD 64
#define NL 3
#define NE_PAD (NE + NN * 16)   // worst-case padded edge count (1.6M, 12.8 MB)

__device__ __forceinline__ float rlane(float v, int l) {
    return __int_as_float(__builtin_amdgcn_readlane(__float_as_int(v), l));
}

// ---------------------------------------------------------------------------
// CSR build, step 1: in-degree histogram; atomicAdd return = edge's rank
// within its dst segment (stored contiguously) -> atomic-free reorder.
// ---------------------------------------------------------------------------
__global__ void hist_kernel(const int* __restrict__ dst,
                            int* __restrict__ deg,
                            int* __restrict__ rank) {
    int t = blockIdx.x * blockDim.x + threadIdx.x;
    int e = t * 4;
    if (e + 4 <= NE) {
        int4 d4 = *reinterpret_cast<const int4*>(dst + e);
        int r0 = atomicAdd(&deg[d4.x], 1);
        int r1 = atomicAdd(&deg[d4.y], 1);
        int r2 = atomicAdd(&deg[d4.z], 1);
        int r3 = atomicAdd(&deg[d4.w], 1);
        *reinterpret_cast<int4*>(rank + e) = make_int4(r0, r1, r2, r3);
    } else {
        for (int i = e; i < NE; ++i) rank[i] = atomicAdd(&deg[dst[i]], 1);
    }
}

// ---------------------------------------------------------------------------
// CSR build, step 2: unordered segment allocation, degrees rounded up to x16
// (pad slots stay zero from the e_sw memset -> (src=0, w=0.0) no-op edges).
// ---------------------------------------------------------------------------
__global__ void alloc_kernel(const int* __restrict__ deg,
                             int* __restrict__ row_start,
                             int* __restrict__ counter) {
    int n = blockIdx.x * blockDim.x + threadIdx.x;
    int lane = threadIdx.x & 63;
    int d = (n < NN) ? ((deg[n] + 15) & ~15) : 0;
    int s = d;
    #pragma unroll
    for (int off = 1; off < 64; off <<= 1) {
        int t = __shfl_up(s, off);
        if (lane >= off) s += t;
    }
    int total = __shfl(s, 63);
    int base = 0;
    if (lane == 63) base = atomicAdd(counter, total);
    base = __shfl(base, 63);
    int my = base + s - d;
    if (n < NN) row_start[n] = my;
}

// ---------------------------------------------------------------------------
// CSR build, step 3: reorder edges to row_start[dst] + rank -- no atomics.
// ---------------------------------------------------------------------------
__global__ void reorder_kernel(const int* __restrict__ src,
                               const int* __restrict__ dst,
                               const float* __restrict__ w,
                               const int* __restrict__ rank,
                               const int* __restrict__ row_start,
                               int2* __restrict__ e_sw) {
    int t = blockIdx.x * blockDim.x + threadIdx.x;
    int e = t * 2;
    if (e + 2 <= NE) {
        int2   s2 = *reinterpret_cast<const int2*>(src + e);
        int2   d2 = *reinterpret_cast<const int2*>(dst + e);
        float2 w2 = *reinterpret_cast<const float2*>(w + e);
        int2   r2 = *reinterpret_cast<const int2*>(rank + e);
        e_sw[row_start[d2.x] + r2.x] = make_int2(s2.x, __float_as_int(w2.x));
        e_sw[row_start[d2.y] + r2.y] = make_int2(s2.y, __float_as_int(w2.y));
    } else {
        for (int i = e; i < NE; ++i) {
            e_sw[row_start[dst[i]] + rank[i]] = make_int2(src[i], __float_as_int(w[i]));
        }
    }
}

// ---------------------------------------------------------------------------
// Gather (lean, SPLIT — round-15 lesson: fusing dense in costs the gather its
// 8-waves/SIMD residency, net -25us/layer): 4 rows per dwordx4 instruction.
// Lane L reads float4 of row src[edge(L>>4)] at cols (L&15)*4 -> one
// global_load_dwordx4 covers 4 edges (1KB in flight per vmcnt slot).
// Edge meta s_loaded (uniform addr), distributed via cndmask chains.
// Epilogue: shfl_xor(16/32) butterfly; lanes 0-15 store the 256B row.
// Segments padded to x16 -> no tails. (256,8) caps at 64 VGPR, no spill.
// ---------------------------------------------------------------------------
__global__ void __launch_bounds__(256, 8)
gather_kernel(const float* __restrict__ h,
              const int* __restrict__ row_start,
              const int* __restrict__ deg,
              const int2* __restrict__ e_sw,
              float* __restrict__ agg) {
    int wid = __builtin_amdgcn_readfirstlane((int)((blockIdx.x * blockDim.x + threadIdx.x) >> 6));
    if (wid >= NN) return;
    const int lane = threadIdx.x & 63;
    const int g    = lane >> 4;          // edge sub-group 0..3
    const int cq   = (lane & 15) << 2;   // this lane's 4-column base
    const int beg  = __builtin_amdgcn_readfirstlane(row_start[wid]);
    const int rdeg = __builtin_amdgcn_readfirstlane((deg[wid] + 15) & ~15);

    float ax0=0.f, ay0=0.f, az0=0.f, aw0=0.f;
    float ax1=0.f, ay1=0.f, az1=0.f, aw1=0.f;
    float ax2=0.f, ay2=0.f, az2=0.f, aw2=0.f;
    float ax3=0.f, ay3=0.f, az3=0.f, aw3=0.f;

    for (int i = 0; i < rdeg; i += 16) {
        const int2* ep = e_sw + beg + i;       // uniform -> s_load path
        int2 m0 = ep[0],  m1 = ep[1],  m2 = ep[2],  m3 = ep[3];
        int2 m4 = ep[4],  m5 = ep[5],  m6 = ep[6],  m7 = ep[7];
        int2 m8 = ep[8],  m9 = ep[9],  m10= ep[10], m11= ep[11];
        int2 m12= ep[12], m13= ep[13], m14= ep[14], m15= ep[15];

#define SLOT(AX,AY,AZ,AW, EA,EB,EC,ED)                                          \
        {                                                                       \
            int  srcg = (g==0) ? EA.x : (g==1) ? EB.x : (g==2) ? EC.x : ED.x;   \
            int  wig  = (g==0) ? EA.y : (g==1) ? EB.y : (g==2) ? EC.y : ED.y;   \
            float wg  = __int_as_float(wig);                                    \
            const float4 r = *reinterpret_cast<const float4*>(                  \
                h + (size_t)srcg * DD + cq);                                    \
            AX += wg * r.x; AY += wg * r.y; AZ += wg * r.z; AW += wg * r.w;     \
        }
        SLOT(ax0,ay0,az0,aw0, m0,m1,m2,m3)
        SLOT(ax1,ay1,az1,aw1, m4,m5,m6,m7)
        SLOT(ax2,ay2,az2,aw2, m8,m9,m10,m11)
        SLOT(ax3,ay3,az3,aw3, m12,m13,m14,m15)
#undef SLOT
    }

    float tx = (ax0+ax1)+(ax2+ax3);
    float ty = (ay0+ay1)+(ay2+ay3);
    float tz = (az0+az1)+(az2+az3);
    float tw = (aw0+aw1)+(aw2+aw3);
    tx += __shfl_xor(tx, 16); tx += __shfl_xor(tx, 32);
    ty += __shfl_xor(ty, 16); ty += __shfl_xor(ty, 32);
    tz += __shfl_xor(tz, 16); tz += __shfl_xor(tz, 32);
    tw += __shfl_xor(tw, 16); tw += __shfl_xor(tw, 32);

    if (lane < 16) {
        float4 t = make_float4(tx, ty, tz, tw);
        *reinterpret_cast<float4*>(agg + (size_t)wid * DD + cq) = t;
    }
}

// ---------------------------------------------------------------------------
// Dense: out[n][lane] = b[lane] + sum_k agg[n][k]*Wrel[k][lane]
//                                + h[n][k]*Wroot[k][lane]   (+tanh on last)
// readlane broadcasts of the wave-resident agg/h rows vs W columns (L1-hot).
// (256,3): spill-free (round-8: tighter cap spills). In-place safe.
// ---------------------------------------------------------------------------
template<bool LAST>
__global__ void __launch_bounds__(256, 3)
dense_kernel(const float* __restrict__ agg,
             const float* h,
             const float* __restrict__ Wrel,
             const float* __restrict__ Wroot,
             const float* __restrict__ b,
             float* hout) {
    const int lane   = threadIdx.x & 63;
    const int wgid   = __builtin_amdgcn_readfirstlane((int)((blockIdx.x * blockDim.x + threadIdx.x) >> 6));
    const int nwaves = (gridDim.x * blockDim.x) >> 6;

    float w1[DD], w2[DD];
    #pragma unroll
    for (int k = 0; k < DD; ++k) {
        w1[k] = Wrel[k * DD + lane];
        w2[k] = Wroot[k * DD + lane];
    }
    const float bias = b[lane];

    for (int n = wgid; n < NN; n += nwaves) {
        const float vagg = agg[(size_t)n * DD + lane];
        const float vh   = h[(size_t)n * DD + lane];
        float a0 = bias, a1 = 0.f, a2 = 0.f, a3 = 0.f;
        #pragma unroll
        for (int k = 0; k < DD; k += 2) {
            float sa0 = rlane(vagg, k),     sh0 = rlane(vh, k);
            float sa1 = rlane(vagg, k + 1), sh1 = rlane(vh, k + 1);
            a0 += sa0 * w1[k];
            a1 += sh0 * w2[k];
            a2 += sa1 * w1[k + 1];
            a3 += sh1 * w2[k + 1];
        }
        float r = (a0 + a1) + (a2 + a3);
        if (LAST) r = tanhf(r);
        hout[(size_t)n * DD + lane] = r;
    }
}

extern "C" void kernel_launch(void* const* d_in, const int* in_sizes, int n_in,
                              void* d_out, int out_size, void* d_ws, size_t ws_size,
                              hipStream_t stream) {
    const float* x     = (const float*)d_in[0];
    const int*   ei    = (const int*)d_in[1];
    const float* ew    = (const float*)d_in[2];
    const float* Wrel  = (const float*)d_in[3];
    const float* brel  = (const float*)d_in[4];
    const float* Wroot = (const float*)d_in[5];
    float* out = (float*)d_out;

    // Workspace (~45 MB of 256 MiB). e_sw/deg/counter contiguous -> ONE memset.
    float* agg       = (float*)d_ws;                    // NN*DD f32 (12.8 MB)
    float* hA        = agg + (size_t)NN * DD;           // NN*DD f32 (12.8 MB)
    int2*  e_sw      = (int2*)(hA + (size_t)NN * DD);   // NE_PAD int2 (12.8 MB)
    int*   deg       = (int*)(e_sw + NE_PAD);           // NN
    int*   counter   = deg + NN;                        // 1
    int*   row_start = counter + 1;                     // NN
    int*   rank      = row_start + NN;                  // NE (3.2 MB)

    const int* src = ei;            // edge_index[0]
    const int* dst = ei + NE;       // edge_index[1]

    const int hblocks = (NE / 4 + 255) / 256;           // 782
    const int rblocks = (NE / 2 + 255) / 256;           // 1563
    const int ablocks = (NN + 255) / 256;               // 196
    const int gblocks = (NN * 64 + 255) / 256;          // 12500 (1 wave/node)
    const int dblocks = 1024;                           // 4096 waves

    // ---- CSR build: one memset covers e_sw pads + deg + counter ----
    hipMemsetAsync(e_sw, 0, (size_t)NE_PAD * sizeof(int2) + (size_t)(NN + 1) * sizeof(int), stream);
    hist_kernel<<<hblocks, 256, 0, stream>>>(dst, deg, rank);
    alloc_kernel<<<ablocks, 256, 0, stream>>>(deg, row_start, counter);
    reorder_kernel<<<rblocks, 256, 0, stream>>>(src, dst, ew, rank, row_start, e_sw);

    // ---- 3 layers: gather -> dense (dense in-place on hA) ----
    gather_kernel<<<gblocks, 256, 0, stream>>>(x, row_start, deg, e_sw, agg);
    dense_kernel<false><<<dblocks, 256, 0, stream>>>(agg, x, Wrel, Wroot, brel, hA);
    gather_kernel<<<gblocks, 256, 0, stream>>>(hA, row_start, deg, e_sw, agg);
    dense_kernel<false><<<dblocks, 256, 0, stream>>>(agg, hA, Wrel + DD*DD, Wroot + DD*DD, brel + DD, hA);
    gather_kernel<<<gblocks, 256, 0, stream>>>(hA, row_start, deg, e_sw, agg);
    dense_kernel<true ><<<dblocks, 256, 0, stream>>>(agg, hA, Wrel + 2*DD*DD, Wroot + 2*DD*DD, brel + 2*DD, out);
}